// Round 6
// baseline (120.836 us; speedup 1.0000x reference)
//
#include <hip/hip_runtime.h>
#include <math.h>

#define KS    5
#define K2    25
#define BB    4
#define HH    256
#define WW    256
#define PLANE (HH * WW)
#define TW    128    // tile width in px (width-split: 2 blocks per 2-row band)
#define LROWD 136    // dwords per tile row: [2 halo][128 px][2 halo][4 pad]
#define PTILE 820    // 6 rows * 136 + 4 pad; 2*PTILE % 32 == 8 -> cg offset 8 banks
#define BSTR  (4 * PTILE + LROWD)   // LDS buffer stride: 4 pair-tiles + dump row
#define DUMPO (4 * PTILE)           // dump row offset inside each buffer
#define NTHR  128
#define NSEG  816    // 4 pairs * 6 rows * 34 float4-segs
#define SPT   7      // staging tasks per thread = ceil(816/128)

typedef __attribute__((ext_vector_type(2))) _Float16 half2_t;
typedef __attribute__((ext_vector_type(4))) float    f32x4;

static __device__ __forceinline__ half2_t u2h(unsigned u) { return __builtin_bit_cast(half2_t, u); }

static __device__ __forceinline__ unsigned pkrtz(float a, float b) {
    auto h = __builtin_amdgcn_cvt_pkrtz(a, b);   // __fp16 ext_vector(2), 4 bytes
    return __builtin_bit_cast(unsigned, h);
}

static __device__ __forceinline__ float dot2(half2_t a, half2_t b, float c) {
#if __has_builtin(__builtin_amdgcn_fdot2)
    return __builtin_amdgcn_fdot2(a, b, c, false);
#else
    return (float)a.x * (float)b.x + ((float)a.y * (float)b.y + c);
#endif
}

// Block = 2 output rows x 128 cols, 2 waves, 4 px/thread, channel-pair f16 tile.
// 8 stages x 8 channels (score: 32..63, output: 0..31), double-buffered LDS.
//
// ROUND 6 RESTRUCTURE (occupancy streams + real register budget):
//  * Width-split: grid 512 -> 1024 blocks (2 w-halves x 128 hgroups x 4 b).
//    LDS/block 59.9 KB -> 26.8 KB => 4 resident blocks/CU instead of 2.
//    Same 8 waves/CU, but 4 INDEPENDENT barrier domains: per-CU phases
//    (VALU 12.5us + LDS 8.5 + VMEM ~9 + drains ~5 were running as a SUM
//    = 41us) can now overlap across streams toward the max.
//  * amdgpu_waves_per_eu(2,2): the compiler was chasing the phantom
//    4-wave/SIMD 128-VGPR step (LDS caps us at 2 waves/SIMD regardless)
//    and shuffling s[4][25] through AGPRs (+~1500 VALU instr -- measured
//    VALUBusy is 2x the hand count). Pinning waves/EU grants the true
//    256-reg budget.
//  * Staging: 7 flat float4 tasks/thread over 4 pairs x 6 rows x 34 segs.
//    Image-edge columns: loads are column-clamped; the two straddling
//    cases (c0==-2 left, c0==254 right) select shifted components; OOB
//    uint2 halves route to a per-lane dump slot so init-zeros provide the
//    padding. OOB rows route whole tasks to dump (tile rows stay zero).
//  * Keeps r4's proven volatile-asm prefetch + manual vmcnt(0) drain.
__global__ __launch_bounds__(NTHR, 4) __attribute__((amdgpu_waves_per_eu(2, 2)))
void local_attn_kernel(const float* __restrict__ x,
                       const float* __restrict__ kern,
                       float* __restrict__ out)
{
    __shared__ unsigned ldsu[2 * BSTR];
    __shared__ float kw[K2];

    const int tid = threadIdx.x;
    for (int i = tid; i < 2 * BSTR; i += NTHR) ldsu[i] = 0u;
    if (tid < K2) kw[tid] = kern[tid] * (1.0f / KS);

    const int lane = tid & 63;
    const int ty   = tid >> 6;          // wave -> output row in block (0/1)
    const int cg   = lane >> 5;         // pair-half (0/1)
    const int txg  = lane & 31;         // pixel-group 0..31
    const int w0   = txg << 2;          // tile dword base (= px base in tile)

    // grid.x = 256: wseg (width half) in bit0, hgroup band swizzled per XCD
    const int bx     = blockIdx.x;
    const int wseg   = bx & 1;
    const int bxh    = bx >> 1;                      // 0..127
    const int hgroup = ((bxh & 7) << 4) | (bxh >> 3); // 16 bands per XCD
    const int h0     = hgroup * 2;
    const int h      = h0 + ty;
    const int wbase  = wseg * TW;
    const int b      = blockIdx.y;

    const float* xb = x + (size_t)b * 64 * PLANE;

    // ---- staging task precompute: task i covers float4-seg (pair,row,sg) ----
    int gofs[SPT], pofs[SPT], lofsA[SPT], lofsB[SPT];
    bool lsh[SPT], rsh[SPT];
#pragma unroll
    for (int i = 0; i < SPT; ++i) {
        const int seg0 = tid + i * NTHR;
        const bool segv = seg0 < NSEG;
        const int seg  = segv ? seg0 : NSEG - 1;
        const int pair = seg / 204;              // 6 rows * 34 segs
        const int rem  = seg - pair * 204;
        const int row  = rem / 34;
        const int sg   = rem - row * 34;
        const int r    = h0 - 2 + row;
        const bool rv  = (unsigned)r < (unsigned)HH;
        const int c0   = wbase - 2 + sg * 4;     // image col of tile dword sg*4
        const int cl   = min(max(c0, 0), WW - 4); // clamped float4 load col
        gofs[i] = min(max(r, 0), HH - 1) * WW + cl;
        pofs[i] = pair * 2 * PLANE;
        const int db = row * LROWD + sg * 4;
        // per-uint2 validity (uint2 halves are col-pair aligned: c0 is even)
        const bool Av = segv && rv && (sg < 33) && (c0 >= 0) && (c0 + 1 < WW);
        const bool Bv = segv && rv && (sg < 33) && (c0 + 3 < WW);
        lsh[i] = (c0 == -2);        // left image edge: valid cols 0,1 in comps x,y
        rsh[i] = (c0 == WW - 2);    // right image edge: valid cols 254,255 in z,w
        const int dump = DUMPO + (tid & 31) * 4; // per-lane dump slot (never read)
        lofsA[i] = Av ? pair * PTILE + db     : dump;
        lofsB[i] = Bv ? pair * PTILE + db + 2 : dump + 2;
    }

    f32x4 pa[SPT], pb[SPT];
    auto prefetch = [&](int st) {
        const float* xc = xb + (size_t)((st < 4) ? 32 + st * 8 : (st - 4) * 8) * PLANE;
#pragma unroll
        for (int i = 0; i < SPT; ++i) {
            const float* p0 = xc + pofs[i] + gofs[i];
            const float* p1 = p0 + PLANE;
            // volatile asm: unsinkable, pinned at stage top in program order
            asm volatile("global_load_dwordx4 %0, %1, off"
                         : "=v"(pa[i]) : "v"(p0));
            asm volatile("global_load_dwordx4 %0, %1, off"
                         : "=v"(pb[i]) : "v"(p1));
        }
        __builtin_amdgcn_sched_barrier(0);
    };
    auto cvtwrite = [&](int bufi) {
        // compiler can't track the asm loads' vmcnt -- wait manually, and
        // fence the scheduler so pkrtz/ds_write can't hoist above the wait.
        asm volatile("s_waitcnt vmcnt(0)" ::: "memory");
        __builtin_amdgcn_sched_barrier(0);
        unsigned* lb = ldsu + bufi * BSTR;
#pragma unroll
        for (int i = 0; i < SPT; ++i) {
            const unsigned d0 = pkrtz(pa[i].x, pb[i].x);
            const unsigned d1 = pkrtz(pa[i].y, pb[i].y);
            const unsigned d2 = pkrtz(pa[i].z, pb[i].z);
            const unsigned d3 = pkrtz(pa[i].w, pb[i].w);
            // edge component shift: load was col-clamped, so straddling segs
            // source their valid uint2 from shifted components.
            const uint2 sA = rsh[i] ? make_uint2(d2, d3) : make_uint2(d0, d1);
            const uint2 sB = lsh[i] ? make_uint2(d0, d1) : make_uint2(d2, d3);
            *(uint2*)(lb + lofsA[i]) = sA;
            *(uint2*)(lb + lofsB[i]) = sB;
        }
    };

    float s[4][K2];
#pragma unroll
    for (int p = 0; p < 4; ++p)
#pragma unroll
        for (int k = 0; k < K2; ++k) s[p][k] = 0.0f;

    __syncthreads();          // zero-init + kw visible
    prefetch(0);
    cvtwrite(0);
    __syncthreads();

#pragma unroll 1
    for (int t = 0; t < 8; ++t) {
        if (t + 1 < 8) prefetch(t + 1);
        const unsigned* buf = ldsu + (t & 1) * BSTR;

        if (t < 4) {
            // ---- score: 2 channel-pairs per lane-half, dot2 accumulate ----
#pragma unroll
            for (int dp = 0; dp < 2; ++dp) {
                const unsigned* tb = buf + (cg * 2 + dp) * PTILE;
                half2_t ctr[4];
                {   // center row (i=2) first: f[q] = pair at px w0-2+q
                    const unsigned* rp = tb + (ty + 2) * LROWD + w0;
                    const uint4 r0 = *(const uint4*)(rp);
                    const uint4 r1 = *(const uint4*)(rp + 4);
                    half2_t f[8] = {u2h(r0.x), u2h(r0.y), u2h(r0.z), u2h(r0.w),
                                    u2h(r1.x), u2h(r1.y), u2h(r1.z), u2h(r1.w)};
#pragma unroll
                    for (int p = 0; p < 4; ++p) ctr[p] = f[p + 2];
#pragma unroll
                    for (int j = 0; j < KS; ++j)
#pragma unroll
                        for (int p = 0; p < 4; ++p)
                            s[p][2 * KS + j] = dot2(f[p + j], ctr[p], s[p][2 * KS + j]);
                }
#pragma unroll
                for (int i = 0; i < KS; ++i) {
                    if (i == 2) continue;
                    const unsigned* rp = tb + (ty + i) * LROWD + w0;
                    const uint4 r0 = *(const uint4*)(rp);
                    const uint4 r1 = *(const uint4*)(rp + 4);
                    half2_t f[8] = {u2h(r0.x), u2h(r0.y), u2h(r0.z), u2h(r0.w),
                                    u2h(r1.x), u2h(r1.y), u2h(r1.z), u2h(r1.w)};
#pragma unroll
                    for (int j = 0; j < KS; ++j)
#pragma unroll
                        for (int p = 0; p < 4; ++p)
                            s[p][i * KS + j] = dot2(f[p + j], ctr[p], s[p][i * KS + j]);
                }
            }
            if (t == 3) {
                // combine pair-halves, then softmax over 25 taps.
                // zero-padded taps score exactly 0 and keep their denominator
                // share (matches reference).
#pragma unroll
                for (int p = 0; p < 4; ++p)
#pragma unroll
                    for (int k = 0; k < K2; ++k)
                        s[p][k] += __shfl_xor(s[p][k], 32, 64);
#pragma unroll
                for (int p = 0; p < 4; ++p) {
                    float mx = -INFINITY;
#pragma unroll
                    for (int k = 0; k < K2; ++k) {
                        float v = s[p][k] * kw[k];
                        s[p][k] = v;
                        mx = fmaxf(mx, v);
                    }
                    float sum = 0.0f;
#pragma unroll
                    for (int k = 0; k < K2; ++k) {
                        float e = __expf(s[p][k] - mx);
                        s[p][k] = e;
                        sum += e;
                    }
                    const float inv = 1.0f / sum;
#pragma unroll
                    for (int k = 0; k < K2; ++k) s[p][k] *= inv;
                }
            }
        } else {
            // ---- output: weighted sum; fp32 accumulate via mixed FMA ----
            const int chb = (t - 4) * 8;
#pragma unroll
            for (int dp = 0; dp < 2; ++dp) {
                const unsigned* tb = buf + (cg * 2 + dp) * PTILE;
                float alo[4] = {0.f, 0.f, 0.f, 0.f};
                float ahi[4] = {0.f, 0.f, 0.f, 0.f};
#pragma unroll
                for (int i = 0; i < KS; ++i) {
                    const unsigned* rp = tb + (ty + i) * LROWD + w0;
                    const uint4 r0 = *(const uint4*)(rp);
                    const uint4 r1 = *(const uint4*)(rp + 4);
                    half2_t f[8] = {u2h(r0.x), u2h(r0.y), u2h(r0.z), u2h(r0.w),
                                    u2h(r1.x), u2h(r1.y), u2h(r1.z), u2h(r1.w)};
#pragma unroll
                    for (int j = 0; j < KS; ++j)
#pragma unroll
                        for (int p = 0; p < 4; ++p) {
                            const half2_t v = f[p + j];
                            const float  wgt = s[p][i * KS + j];
                            alo[p] = fmaf((float)v.x, wgt, alo[p]);
                            ahi[p] = fmaf((float)v.y, wgt, ahi[p]);
                        }
                }
                const int c0 = chb + (cg * 2 + dp) * 2;
                float* op = out + ((size_t)b * 32 + c0) * PLANE + h * WW + wbase + w0;
                *(float4*)op           = make_float4(alo[0], alo[1], alo[2], alo[3]);
                *(float4*)(op + PLANE) = make_float4(ahi[0], ahi[1], ahi[2], ahi[3]);
            }
        }

        if (t + 1 < 8) {
            cvtwrite((t + 1) & 1);
            __syncthreads();
        }
    }
}

extern "C" void kernel_launch(void* const* d_in, const int* in_sizes, int n_in,
                              void* d_out, int out_size, void* d_ws, size_t ws_size,
                              hipStream_t stream) {
    const float* x    = (const float*)d_in[0];
    const float* kern = (const float*)d_in[1];
    float*       out  = (float*)d_out;

    dim3 grid(2 * (HH / 2), BB, 1);   // 2 width-halves x 128 row-bands, 4 batch
    dim3 block(NTHR, 1, 1);
    hipLaunchKernelGGL(local_attn_kernel, grid, block, 0, stream, x, kern, out);
}

// Round 7
// 116.569 us; speedup vs baseline: 1.0366x; 1.0366x over previous
//
#include <hip/hip_runtime.h>
#include <math.h>

#define KS    5
#define K2    25
#define BB    4
#define HH    256
#define WW    256
#define PLANE (HH * WW)
#define LROWD 264     // dwords per tile row: [2 halo][256 px][2 halo][4 pad]
#define PTILE 1864    // 7 rows * 264 + 16 pad; %32==8 -> cg stride (2*PTILE) == 16 banks
#define NTHR  320     // 4 consumer waves + 1 producer wave

typedef __attribute__((ext_vector_type(2))) _Float16 half2_t;
typedef __attribute__((ext_vector_type(4))) float    f32x4;

static __device__ __forceinline__ half2_t u2h(unsigned u) { return __builtin_bit_cast(half2_t, u); }

static __device__ __forceinline__ unsigned pkrtz(float a, float b) {
    auto h = __builtin_amdgcn_cvt_pkrtz(a, b);   // __fp16 ext_vector(2), 4 bytes
    return __builtin_bit_cast(unsigned, h);
}

static __device__ __forceinline__ float dot2(half2_t a, half2_t b, float c) {
#if __has_builtin(__builtin_amdgcn_fdot2)
    return __builtin_amdgcn_fdot2(a, b, c, false);
#else
    return (float)a.x * (float)b.x + ((float)a.y * (float)b.y + c);
#endif
}

// ROUND 7: producer/consumer wave specialization on the r4 tile structure.
// Block = 2 output rows x 256 cols. 4 CONSUMER waves (r4's compute verbatim:
// 4 px/thread, channel-pair f16 tile, dot2 scores, mixed-FMA output) + 1
// PRODUCER wave doing ALL staging (global->pkrtz->LDS, 24 tasks/stage,
// pair-pipelined 2-deep, counted vmcnt(12) so one pair converts while the
// next is in flight). Rationale: r0-r6 showed per-CU time = SUM of phases
// (VALU 12us + LDS 8-13 + VMEM ~9 + drains) because every wave carried all
// three workloads between the same barriers; specialization makes staging
// latency/writes run concurrently with compute waves.
// Roles live in DISJOINT top-level branches so consumer state (s[4][25],
// ~100 VGPR) is dead on the producer path and staging regs (A/B, 96 VGPR)
// dead on the consumer path: pressure = max, not sum (~150 < 170 budget at
// 10 waves/CU). Barrier counts matched exactly (9 per role after common
// init barrier) -- s_barrier is arrival-counted per wave on CDNA.
// Double-buffer parity: stage st lives in buf[st&1]; producer writes st=t+1
// while consumers read st=t.
__global__ __launch_bounds__(NTHR, 2)
void local_attn_kernel(const float* __restrict__ x,
                       const float* __restrict__ kern,
                       float* __restrict__ out)
{
    __shared__ unsigned ldsu[2 * 4 * PTILE];
    __shared__ float kw[K2];

    const int tid = threadIdx.x;
    for (int i = tid; i < 2 * 4 * PTILE; i += NTHR) ldsu[i] = 0u;
    if (tid < K2) kw[tid] = kern[tid] * (1.0f / KS);

    const int lane = tid & 63;
    const int wv   = tid >> 6;                      // 0..3 consumers, 4 producer

    // XCD swizzle: each XCD owns a contiguous 32-row band (halo L2-shared)
    const int bx     = blockIdx.x;
    const int hgroup = ((bx & 7) << 4) | (bx >> 3);
    const int h0     = hgroup * 2;
    const int b      = blockIdx.y;

    const float* xb = x + (size_t)b * 64 * PLANE;

    __syncthreads();          // B0 (common): zero-init + kw visible

    if (wv == 4) {
        // ================= PRODUCER WAVE =================
        // lane covers px [4*lane, 4*lane+4) of each (pair, row).
        int grow[6], lrow[6];
#pragma unroll
        for (int rr = 0; rr < 6; ++rr) {
            const int r  = h0 - 2 + rr;
            const bool v = (unsigned)r < (unsigned)HH;
            grow[rr] = min(max(r, 0), HH - 1) * WW + lane * 4;
            lrow[rr] = (v ? rr : 6) * LROWD + 2 + lane * 4;   // row 6 = dump
        }

        f32x4 A0[6], B0[6], A1[6], B1[6];   // 2 pair-slots in flight (96 VGPR)

        auto issue = [&](const float* xc, int pair, f32x4* A, f32x4* B) {
#pragma unroll
            for (int rr = 0; rr < 6; ++rr) {
                const float* p0 = xc + pair * 2 * PLANE + grow[rr];
                const float* p1 = p0 + PLANE;
                asm volatile("global_load_dwordx4 %0, %1, off" : "=v"(A[rr]) : "v"(p0));
                asm volatile("global_load_dwordx4 %0, %1, off" : "=v"(B[rr]) : "v"(p1));
            }
        };
        auto cvtw = [&](unsigned* lb, int pair, const f32x4* A, const f32x4* B) {
#pragma unroll
            for (int rr = 0; rr < 6; ++rr) {
                unsigned* wp = lb + pair * PTILE + lrow[rr];
                const unsigned d0 = pkrtz(A[rr].x, B[rr].x);
                const unsigned d1 = pkrtz(A[rr].y, B[rr].y);
                const unsigned d2 = pkrtz(A[rr].z, B[rr].z);
                const unsigned d3 = pkrtz(A[rr].w, B[rr].w);
                *(uint2*)(wp)     = make_uint2(d0, d1);
                *(uint2*)(wp + 2) = make_uint2(d2, d3);
            }
        };
        auto stage = [&](int st) {
            const float* xc = xb + (size_t)((st < 4) ? 32 + st * 8 : (st - 4) * 8) * PLANE;
            unsigned* lb = ldsu + (st & 1) * 4 * PTILE;
            issue(xc, 0, A0, B0);
            issue(xc, 1, A1, B1);
            asm volatile("s_waitcnt vmcnt(12)" ::: "memory");   // pair0 done
            __builtin_amdgcn_sched_barrier(0);
            cvtw(lb, 0, A0, B0);
            issue(xc, 2, A0, B0);
            asm volatile("s_waitcnt vmcnt(12)" ::: "memory");   // pair1 done
            __builtin_amdgcn_sched_barrier(0);
            cvtw(lb, 1, A1, B1);
            issue(xc, 3, A1, B1);
            asm volatile("s_waitcnt vmcnt(12)" ::: "memory");   // pair2 done
            __builtin_amdgcn_sched_barrier(0);
            cvtw(lb, 2, A0, B0);
            asm volatile("s_waitcnt vmcnt(0)" ::: "memory");    // pair3 done
            __builtin_amdgcn_sched_barrier(0);
            cvtw(lb, 3, A1, B1);
        };

        stage(0);
        __syncthreads();                        // B1: buf0 ready
#pragma unroll 1
        for (int t = 0; t < 8; ++t) {
            if (t < 7) stage(t + 1);
            __syncthreads();                    // B2..B9
        }
    } else {
        // ================= CONSUMER WAVES (r4 compute verbatim) =============
        const int ty = wv >> 1;                       // output row in block
        const int cg = lane >> 5;                     // pair-half (0/1)
        const int tx = ((wv & 1) << 5) | (lane & 31); // pixel-group 0..63
        const int w0 = tx << 2;
        const int h  = h0 + ty;

        float s[4][K2];
#pragma unroll
        for (int p = 0; p < 4; ++p)
#pragma unroll
            for (int k = 0; k < K2; ++k) s[p][k] = 0.0f;

        __syncthreads();                        // B1: buf0 ready
#pragma unroll 1
        for (int t = 0; t < 8; ++t) {
            const unsigned* buf = ldsu + (t & 1) * 4 * PTILE;

            if (t < 4) {
                // ---- score: 2 channel-pairs per lane-half, dot2 accumulate ----
#pragma unroll
                for (int dp = 0; dp < 2; ++dp) {
                    const unsigned* tb = buf + (cg * 2 + dp) * PTILE;
                    half2_t ctr[4];
                    {   // center row (i=2) first: f[q] = pair at px w0-2+q
                        const unsigned* rp = tb + (ty + 2) * LROWD + w0;
                        const uint4 r0 = *(const uint4*)(rp);
                        const uint4 r1 = *(const uint4*)(rp + 4);
                        half2_t f[8] = {u2h(r0.x), u2h(r0.y), u2h(r0.z), u2h(r0.w),
                                        u2h(r1.x), u2h(r1.y), u2h(r1.z), u2h(r1.w)};
#pragma unroll
                        for (int p = 0; p < 4; ++p) ctr[p] = f[p + 2];
#pragma unroll
                        for (int j = 0; j < KS; ++j)
#pragma unroll
                            for (int p = 0; p < 4; ++p)
                                s[p][2 * KS + j] = dot2(f[p + j], ctr[p], s[p][2 * KS + j]);
                    }
#pragma unroll
                    for (int i = 0; i < KS; ++i) {
                        if (i == 2) continue;
                        const unsigned* rp = tb + (ty + i) * LROWD + w0;
                        const uint4 r0 = *(const uint4*)(rp);
                        const uint4 r1 = *(const uint4*)(rp + 4);
                        half2_t f[8] = {u2h(r0.x), u2h(r0.y), u2h(r0.z), u2h(r0.w),
                                        u2h(r1.x), u2h(r1.y), u2h(r1.z), u2h(r1.w)};
#pragma unroll
                        for (int j = 0; j < KS; ++j)
#pragma unroll
                            for (int p = 0; p < 4; ++p)
                                s[p][i * KS + j] = dot2(f[p + j], ctr[p], s[p][i * KS + j]);
                    }
                }
                if (t == 3) {
                    // combine pair-halves, then softmax over 25 taps.
                    // zero-padded taps score exactly 0 and keep their
                    // denominator share (matches reference).
#pragma unroll
                    for (int p = 0; p < 4; ++p)
#pragma unroll
                        for (int k = 0; k < K2; ++k)
                            s[p][k] += __shfl_xor(s[p][k], 32, 64);
#pragma unroll
                    for (int p = 0; p < 4; ++p) {
                        float mx = -INFINITY;
#pragma unroll
                        for (int k = 0; k < K2; ++k) {
                            float v = s[p][k] * kw[k];
                            s[p][k] = v;
                            mx = fmaxf(mx, v);
                        }
                        float sum = 0.0f;
#pragma unroll
                        for (int k = 0; k < K2; ++k) {
                            float e = __expf(s[p][k] - mx);
                            s[p][k] = e;
                            sum += e;
                        }
                        const float inv = 1.0f / sum;
#pragma unroll
                        for (int k = 0; k < K2; ++k) s[p][k] *= inv;
                    }
                }
            } else {
                // ---- output: weighted sum; fp32 accumulate via mixed FMA ----
                const int chb = (t - 4) * 8;
#pragma unroll
                for (int dp = 0; dp < 2; ++dp) {
                    const unsigned* tb = buf + (cg * 2 + dp) * PTILE;
                    float alo[4] = {0.f, 0.f, 0.f, 0.f};
                    float ahi[4] = {0.f, 0.f, 0.f, 0.f};
#pragma unroll
                    for (int i = 0; i < KS; ++i) {
                        const unsigned* rp = tb + (ty + i) * LROWD + w0;
                        const uint4 r0 = *(const uint4*)(rp);
                        const uint4 r1 = *(const uint4*)(rp + 4);
                        half2_t f[8] = {u2h(r0.x), u2h(r0.y), u2h(r0.z), u2h(r0.w),
                                        u2h(r1.x), u2h(r1.y), u2h(r1.z), u2h(r1.w)};
#pragma unroll
                        for (int j = 0; j < KS; ++j)
#pragma unroll
                            for (int p = 0; p < 4; ++p) {
                                const half2_t v = f[p + j];
                                const float  wgt = s[p][i * KS + j];
                                alo[p] = fmaf((float)v.x, wgt, alo[p]);
                                ahi[p] = fmaf((float)v.y, wgt, ahi[p]);
                            }
                    }
                    const int c0 = chb + (cg * 2 + dp) * 2;
                    float* op = out + ((size_t)b * 32 + c0) * PLANE + h * WW + w0;
                    *(float4*)op           = make_float4(alo[0], alo[1], alo[2], alo[3]);
                    *(float4*)(op + PLANE) = make_float4(ahi[0], ahi[1], ahi[2], ahi[3]);
                }
            }
            __syncthreads();                    // B2..B9
        }
    }
}

extern "C" void kernel_launch(void* const* d_in, const int* in_sizes, int n_in,
                              void* d_out, int out_size, void* d_ws, size_t ws_size,
                              hipStream_t stream) {
    const float* x    = (const float*)d_in[0];
    const float* kern = (const float*)d_in[1];
    float*       out  = (float*)d_out;

    dim3 grid(HH / 2, BB, 1);
    dim3 block(NTHR, 1, 1);
    hipLaunchKernelGGL(local_attn_kernel, grid, block, 0, stream, x, kern, out);
}

// Round 8
// 111.898 us; speedup vs baseline: 1.0799x; 1.0417x over previous
//
#include <hip/hip_runtime.h>
#include <math.h>

#define KS    5
#define K2    25
#define BB    4
#define HH    256
#define WW    256
#define PLANE (HH * WW)
#define LROWD 264     // dwords per tile row: [2 halo][256 px][2 halo][4 pad]
#define PTILE 1864    // 7 rows * 264 + 16 pad
#define NTHR  256

typedef __attribute__((ext_vector_type(2))) _Float16 half2_t;
typedef __attribute__((ext_vector_type(4))) float    f32x4;

static __device__ __forceinline__ half2_t u2h(unsigned u) { return __builtin_bit_cast(half2_t, u); }

static __device__ __forceinline__ unsigned pkrtz(float a, float b) {
    auto h = __builtin_amdgcn_cvt_pkrtz(a, b);   // __fp16 ext_vector(2), 4 bytes
    return __builtin_bit_cast(unsigned, h);
}

static __device__ __forceinline__ float dot2(half2_t a, half2_t b, float c) {
#if __has_builtin(__builtin_amdgcn_fdot2)
    return __builtin_amdgcn_fdot2(a, b, c, false);
#else
    return (float)a.x * (float)b.x + ((float)a.y * (float)b.y + c);
#endif
}

// Block = 2 output rows x 256 cols, 4 waves, 4 px/thread, channel-pair f16 tile.
// 8 stages x 8 channels (score: 32..63, output: 0..31), double-buffered LDS.
//
// ROUND 8: TAP-SPLIT ACCUMULATION (the register-pressure fix).
// Diagnosis r0-r7: every VGPR reading (64/80/96/128/140) is far below the
// ~150-200 live-set arithmetic, and VALU issue is consistently ~2.5x the
// hand-counted ideal -- the s[4][25]=100-reg accumulator has been living in
// AGPRs with v_accvgpr_read/write around every dot2/FMA. All scheduling
// fixes were null because the serial accumulate chain itself was bloated.
// Fix, two coordinated parts of one theory ("free the accumulator"):
//  (a) lane-halves split TAPS instead of CHANNELS: half0 owns taps 0..12
//      (rows 0,1 + row2 j<=2), half1 owns 12..24 (row2 j>=2 + rows 3,4),
//      each over ALL 4 channel pairs (dp 0..3). s[] shrinks 100 -> 52 regs
//      permanently: the output phase is also tap-split with a per-pair
//      shfl_xor(32) combine and half-predicated stores. Register-slot
//      uniformity: row ADDRESSES differ per half (legal), row-2's j-window
//      shifts via 6 cndmask (g[q] = hi ? fc[q+2] : fc[q]); duplicated tap
//      k12 is weight-zeroed on half1. t==3 exchange: 13 shfl + cndmask
//      remap per p; softmax per-p keeps transient liveness ~25 regs.
//  (b) amdgpu_waves_per_eu(2) (min only): 256-VGPR budget at the 2 blocks/CU
//      occupancy LDS already dictates (59.9 KB/block).
// Keeps r4's volatile-asm prefetch (unsinkable) + manual vmcnt(0) drain.
__global__ __launch_bounds__(NTHR, 2) __attribute__((amdgpu_waves_per_eu(2)))
void local_attn_kernel(const float* __restrict__ x,
                       const float* __restrict__ kern,
                       float* __restrict__ out)
{
    __shared__ unsigned ldsu[2 * 4 * PTILE];
    __shared__ float kw[K2];

    const int tid = threadIdx.x;
    for (int i = tid; i < 2 * 4 * PTILE; i += NTHR) ldsu[i] = 0u;
    if (tid < K2) kw[tid] = kern[tid] * (1.0f / KS);

    const int lane = tid & 63;
    const int wv   = tid >> 6;
    const int ty   = wv >> 1;                       // output row in block
    const int cg   = lane >> 5;                     // lane-half (0/1) = tap-half
    const bool hi  = (cg != 0);
    const int tx   = ((wv & 1) << 5) | (lane & 31); // pixel-group 0..63
    const int w0   = tx << 2;

    // XCD swizzle: each XCD owns a contiguous 32-row band (halo L2-shared)
    const int bx     = blockIdx.x;
    const int hgroup = ((bx & 7) << 4) | (bx >> 3);
    const int h0     = hgroup * 2;
    const int h      = h0 + ty;
    const int b      = blockIdx.y;

    const float* xb = x + (size_t)b * 64 * PLANE;

    // 6 staging tasks/thread: task i -> (pair, tile row, 4-px segment)
    int gofs[6], lofs[6], pofs[6];
#pragma unroll
    for (int i = 0; i < 6; ++i) {
        const int rp   = (tid >> 6) + 4 * i;        // 0..23 (wave-uniform)
        const int row  = rp % 6;
        const int pair = rp / 6;
        const int r    = h0 - 2 + row;
        const bool v   = (unsigned)r < (unsigned)HH;
        gofs[i] = min(max(r, 0), HH - 1) * WW + (tid & 63) * 4;
        pofs[i] = pair * 2 * PLANE;
        lofs[i] = pair * PTILE + (v ? row : 6) * LROWD + 2 + (tid & 63) * 4;
    }

    f32x4 pa[6], pb[6];
    auto prefetch = [&](int st) {
        const float* xc = xb + (size_t)((st < 4) ? 32 + st * 8 : (st - 4) * 8) * PLANE;
#pragma unroll
        for (int i = 0; i < 6; ++i) {
            const float* p0 = xc + pofs[i] + gofs[i];
            const float* p1 = p0 + PLANE;
            // volatile asm: unsinkable, pinned at stage top in program order
            asm volatile("global_load_dwordx4 %0, %1, off"
                         : "=v"(pa[i]) : "v"(p0));
            asm volatile("global_load_dwordx4 %0, %1, off"
                         : "=v"(pb[i]) : "v"(p1));
        }
        __builtin_amdgcn_sched_barrier(0);
    };
    auto cvtwrite = [&](int bufi) {
        asm volatile("s_waitcnt vmcnt(0)" ::: "memory");
        __builtin_amdgcn_sched_barrier(0);
        unsigned* lb = ldsu + bufi * 4 * PTILE;
#pragma unroll
        for (int i = 0; i < 6; ++i) {
            const unsigned d0 = pkrtz(pa[i].x, pb[i].x);
            const unsigned d1 = pkrtz(pa[i].y, pb[i].y);
            const unsigned d2 = pkrtz(pa[i].z, pb[i].z);
            const unsigned d3 = pkrtz(pa[i].w, pb[i].w);
            *(uint2*)(lb + lofs[i])     = make_uint2(d0, d1);
            *(uint2*)(lb + lofs[i] + 2) = make_uint2(d2, d3);
        }
    };

    // tap-split accumulator / weights: 13 slots per px.
    // half0: m=lr*5+j (rows 0,1), m=10+jj (row2, j=jj).
    // half1: m=lr*5+j (rows 3,4), m=10+jj (row2, j=jj+2); m10 (k12) is dup.
    float s[4][13];
#pragma unroll
    for (int p = 0; p < 4; ++p)
#pragma unroll
        for (int m = 0; m < 13; ++m) s[p][m] = 0.0f;

    __syncthreads();          // zero-init + kw visible
    prefetch(0);
    cvtwrite(0);
    __syncthreads();

#pragma unroll 1
    for (int t = 0; t < 8; ++t) {
        if (t + 1 < 8) prefetch(t + 1);
        const unsigned* buf = ldsu + (t & 1) * 4 * PTILE;

        if (t < 4) {
            // ---- score: all 4 pairs, own tap-half, dot2 accumulate ----
#pragma unroll
            for (int dp = 0; dp < 4; ++dp) {
                const unsigned* tb = buf + dp * PTILE;
                const unsigned* rA = tb + (ty + (hi ? 3 : 0)) * LROWD + w0;
                const unsigned* rC = tb + (ty + 2) * LROWD + w0;   // row2, both halves
                const uint4 A0 = *(const uint4*)(rA);
                const uint4 A1 = *(const uint4*)(rA + 4);
                const uint4 B0 = *(const uint4*)(rA + LROWD);
                const uint4 B1 = *(const uint4*)(rA + LROWD + 4);
                const uint4 C0 = *(const uint4*)(rC);
                const uint4 C1 = *(const uint4*)(rC + 4);
                const unsigned fa[8] = {A0.x, A0.y, A0.z, A0.w, A1.x, A1.y, A1.z, A1.w};
                const unsigned fb[8] = {B0.x, B0.y, B0.z, B0.w, B1.x, B1.y, B1.z, B1.w};
                const unsigned fc[8] = {C0.x, C0.y, C0.z, C0.w, C1.x, C1.y, C1.z, C1.w};
                half2_t ctr[4];
#pragma unroll
                for (int p = 0; p < 4; ++p) ctr[p] = u2h(fc[p + 2]);
                unsigned g[6];
#pragma unroll
                for (int q = 0; q < 6; ++q) g[q] = hi ? fc[q + 2] : fc[q];
#pragma unroll
                for (int j = 0; j < KS; ++j)
#pragma unroll
                    for (int p = 0; p < 4; ++p)
                        s[p][j] = dot2(u2h(fa[p + j]), ctr[p], s[p][j]);
#pragma unroll
                for (int j = 0; j < KS; ++j)
#pragma unroll
                    for (int p = 0; p < 4; ++p)
                        s[p][5 + j] = dot2(u2h(fb[p + j]), ctr[p], s[p][5 + j]);
#pragma unroll
                for (int jj = 0; jj < 3; ++jj)
#pragma unroll
                    for (int p = 0; p < 4; ++p)
                        s[p][10 + jj] = dot2(u2h(g[p + jj]), ctr[p], s[p][10 + jj]);
            }
            if (t == 3) {
                // exchange tap-halves, softmax over 25, write back local weights.
                // zero-padded taps score exactly 0 and keep their denominator
                // share (matches reference). Processed per-p to bound liveness.
#pragma unroll
                for (int p = 0; p < 4; ++p) {
                    float r[13];
#pragma unroll
                    for (int m = 0; m < 13; ++m) r[m] = __shfl_xor(s[p][m], 32, 64);
                    float sc[K2];
#pragma unroll
                    for (int m = 0; m < 10; ++m) sc[m] = hi ? r[m] : s[p][m];
                    sc[10] = hi ? r[10] : s[p][10];
                    sc[11] = hi ? r[11] : s[p][11];
                    sc[12] = hi ? r[12] : s[p][12];
                    sc[13] = hi ? s[p][11] : r[11];
                    sc[14] = hi ? s[p][12] : r[12];
#pragma unroll
                    for (int m = 0; m < 10; ++m) sc[15 + m] = hi ? s[p][m] : r[m];
                    float mx = -INFINITY;
#pragma unroll
                    for (int k = 0; k < K2; ++k) {
                        float v = sc[k] * kw[k];
                        sc[k] = v;
                        mx = fmaxf(mx, v);
                    }
                    float sum = 0.0f;
#pragma unroll
                    for (int k = 0; k < K2; ++k) {
                        float e = __expf(sc[k] - mx);
                        sc[k] = e;
                        sum += e;
                    }
                    const float inv = 1.0f / sum;
#pragma unroll
                    for (int k = 0; k < K2; ++k) sc[k] *= inv;
                    // write back this half's weight slots (k12 dup zeroed on hi)
#pragma unroll
                    for (int m = 0; m < 10; ++m) s[p][m] = hi ? sc[15 + m] : sc[m];
                    s[p][10] = hi ? 0.0f : sc[10];
                    s[p][11] = hi ? sc[13] : sc[11];
                    s[p][12] = hi ? sc[14] : sc[12];
                }
            }
        } else {
            // ---- output: all 4 pairs, own tap-half, partial + shfl combine ----
            const int chb = (t - 4) * 8;
#pragma unroll
            for (int dp = 0; dp < 4; ++dp) {
                const unsigned* tb = buf + dp * PTILE;
                const unsigned* rA = tb + (ty + (hi ? 3 : 0)) * LROWD + w0;
                const unsigned* rC = tb + (ty + 2) * LROWD + w0;
                const uint4 A0 = *(const uint4*)(rA);
                const uint4 A1 = *(const uint4*)(rA + 4);
                const uint4 B0 = *(const uint4*)(rA + LROWD);
                const uint4 B1 = *(const uint4*)(rA + LROWD + 4);
                const uint4 C0 = *(const uint4*)(rC);
                const uint4 C1 = *(const uint4*)(rC + 4);
                const unsigned fa[8] = {A0.x, A0.y, A0.z, A0.w, A1.x, A1.y, A1.z, A1.w};
                const unsigned fb[8] = {B0.x, B0.y, B0.z, B0.w, B1.x, B1.y, B1.z, B1.w};
                const unsigned fc[8] = {C0.x, C0.y, C0.z, C0.w, C1.x, C1.y, C1.z, C1.w};
                unsigned g[6];
#pragma unroll
                for (int q = 0; q < 6; ++q) g[q] = hi ? fc[q + 2] : fc[q];

                float alo[4] = {0.f, 0.f, 0.f, 0.f};
                float ahi[4] = {0.f, 0.f, 0.f, 0.f};
#pragma unroll
                for (int j = 0; j < KS; ++j)
#pragma unroll
                    for (int p = 0; p < 4; ++p) {
                        const half2_t v = u2h(fa[p + j]);
                        const float  w = s[p][j];
                        alo[p] = fmaf((float)v.x, w, alo[p]);
                        ahi[p] = fmaf((float)v.y, w, ahi[p]);
                    }
#pragma unroll
                for (int j = 0; j < KS; ++j)
#pragma unroll
                    for (int p = 0; p < 4; ++p) {
                        const half2_t v = u2h(fb[p + j]);
                        const float  w = s[p][5 + j];
                        alo[p] = fmaf((float)v.x, w, alo[p]);
                        ahi[p] = fmaf((float)v.y, w, ahi[p]);
                    }
#pragma unroll
                for (int jj = 0; jj < 3; ++jj)
#pragma unroll
                    for (int p = 0; p < 4; ++p) {
                        const half2_t v = u2h(g[p + jj]);
                        const float  w = s[p][10 + jj];
                        alo[p] = fmaf((float)v.x, w, alo[p]);
                        ahi[p] = fmaf((float)v.y, w, ahi[p]);
                    }
                // combine tap-halves: both halves then hold the full sum
#pragma unroll
                for (int p = 0; p < 4; ++p) {
                    alo[p] += __shfl_xor(alo[p], 32, 64);
                    ahi[p] += __shfl_xor(ahi[p], 32, 64);
                }
                const int c0 = chb + dp * 2;
                if (cg == (dp & 1)) {   // half-predicated store, balanced over dp
                    float* op = out + ((size_t)b * 32 + c0) * PLANE + h * WW + w0;
                    *(float4*)op           = make_float4(alo[0], alo[1], alo[2], alo[3]);
                    *(float4*)(op + PLANE) = make_float4(ahi[0], ahi[1], ahi[2], ahi[3]);
                }
            }
        }

        if (t + 1 < 8) {
            cvtwrite((t + 1) & 1);
            __syncthreads();
        }
    }
}

extern "C" void kernel_launch(void* const* d_in, const int* in_sizes, int n_in,
                              void* d_out, int out_size, void* d_ws, size_t ws_size,
                              hipStream_t stream) {
    const float* x    = (const float*)d_in[0];
    const float* kern = (const float*)d_in[1];
    float*       out  = (float*)d_out;

    dim3 grid(HH / 2, BB, 1);
    dim3 block(NTHR, 1, 1);
    hipLaunchKernelGGL(local_attn_kernel, grid, block, 0, stream, x, kern, out);
}